// Round 18
// baseline (286.948 us; speedup 1.0000x reference)
//
#include <hip/hip_runtime.h>
#include <math.h>

#define NU 3   // independent 16-row chains per wave (48 rows/wave)

typedef __attribute__((ext_vector_type(8))) short   short8;   // 8 fp16 bit-container (4 VGPRs)
typedef __attribute__((ext_vector_type(8))) _Float16 half8;
typedef __attribute__((ext_vector_type(2))) __fp16  fp16x2;   // cvt_pkrtz result type
typedef __attribute__((ext_vector_type(4))) float   f32x4;    // MFMA C/D frag

__device__ __forceinline__ half8 as_h8(short8 s) {
  union { short8 s; half8 h; } u; u.s = s; return u.h;
}
#define MFMA16(a,b,c) __builtin_amdgcn_mfma_f32_16x16x32_f16(as_h8(a), as_h8(b), (c), 0, 0, 0)

// ---- ws layout: frag-blocks of 1024 B (64 lanes x 16 B) ----
#define WS_B1W1   0
#define WS_B1W2   12
#define WS_LPW1   20
#define WS_BIAS   24    // 2 frag blocks reused as f32 bias region (512 floats)
#define WS_A1WIN  28
#define WS_A1WOUT 52
#define WS_B2W1   76
#define WS_B2W2   84
#define WS_A2WIN  92
#define WS_A2WOUT 116
#define WS_B3W1   140
#define WS_B3W2   148
#define WS_OUTW   156
#define WS_COMP   164   // 32 composed frags: per rep r (16): CKneg[4], CV[4], G[4], BF[4]
#define WS_FRAGS  196

// f32 -> fp16 (prep + scalar paths)
__device__ __forceinline__ unsigned short f2h(float f) {
  union { _Float16 h; unsigned short u; } r;
  r.h = (_Float16)f;
  return r.u;
}
// packed f32x2 -> fp16x2 (RTZ), single VALU op
__device__ __forceinline__ unsigned int pkrtz(float lo, float hi) {
  union { fp16x2 h; unsigned int u; } r;
  r.h = __builtin_amdgcn_cvt_pkrtz(lo, hi);
  return r.u;
}
// unpack fp16 halves of a uint -> f32 (v_cvt_f32_f16)
__device__ __forceinline__ float h_lo(unsigned int p) {
  union { unsigned short s; _Float16 h; } c; c.s = (unsigned short)p; return (float)c.h;
}
__device__ __forceinline__ float h_hi(unsigned int p) {
  union { unsigned short s; _Float16 h; } c; c.s = (unsigned short)(p >> 16); return (float)c.h;
}

__device__ __forceinline__ short8 pack8(float4 a, float4 b) {
  union { unsigned int u[4]; short8 s; } r;
  r.u[0] = pkrtz(a.x, a.y);
  r.u[1] = pkrtz(a.z, a.w);
  r.u[2] = pkrtz(b.x, b.y);
  r.u[3] = pkrtz(b.z, b.w);
  return r.s;
}

__device__ __forceinline__ short8 zero8() {
  short8 r;
  #pragma unroll
  for (int j = 0; j < 8; ++j) r[j] = 0;
  return r;
}

__device__ __forceinline__ f32x4 relu4(f32x4 v) {
  f32x4 r;
  #pragma unroll
  for (int j = 0; j < 4; ++j) r[j] = fmaxf(v[j], 0.0f);
  return r;
}

// ============ prep: direct weights f32 -> fp16 B-fragments in d_ws ============
// B-frag layout (16x16x32): lane l holds B[k = (l>>4)*8 + j][col = l&15], j=0..7.
__global__ __launch_bounds__(64) void prep_kernel(
    const float* b1w1, const float* b1w2, const float* lpw1, const float* lpw2,
    const float* a1win, const float* a1wout, const float* f1gw, const float* f1bw,
    const float* b2w1, const float* b2w2, const float* a2win, const float* a2wout,
    const float* f2gw, const float* f2bw, const float* b3w1, const float* b3w2,
    const float* outw, unsigned short* ws)
{
  const float* WS_[17] = {b1w1,b1w2,lpw1,lpw2,a1win,a1wout,f1gw,f1bw,b2w1,b2w2,
                          a2win,a2wout,f2gw,f2bw,b3w1,b3w2,outw};
  const int KA[17] = {80,64,40,32,64,64,64,64,64,64,64,64,64,64,64,64,64};
  const int NA[17] = {64,64,32,64,192,64,64,64,64,64,192,64,64,64,64,64,64};
  const int FO[17] = {0,12,20,24,28,52,60,68,76,84,92,116,124,132,140,148,156};

  const int b = blockIdx.x;
  int m = 0;
  #pragma unroll
  for (int i = 1; i < 17; ++i) if (b >= FO[i]) m = i;
  const int f  = b - FO[m];
  const int K  = KA[m], N = NA[m];
  const int kc = (K + 31) >> 5;
  const int n  = f / kc, c = f % kc;

  const int lane = threadIdx.x;
  const int col  = n * 16 + (lane & 15);
  const int kb   = c * 32 + ((lane >> 4) * 8);
  const float* W = WS_[m];

  short8 r;
  #pragma unroll
  for (int j = 0; j < 8; ++j) {
    const int k = kb + j;
    const float v = (k < K) ? W[(size_t)k * N + col] : 0.0f;
    r[j] = (short)f2h(v);
  }
  *reinterpret_cast<short8*>(ws + (size_t)b * 512 + lane * 8) = r;
}

// ============ prep2: composed ye-path matrices and biases ============
// ye = z@lp_w2 + lp_b2  =>  ye@W = z@(lp_w2@W) + (lp_b2@W).
__global__ __launch_bounds__(64) void prep2_kernel(
    const float* lpw2, const float* lpb2,
    const float* a1win, const float* a1bin, const float* a2win, const float* a2bin,
    const float* f1gw, const float* f1gb, const float* f1bw, const float* f1bb,
    const float* f2gw, const float* f2gb, const float* f2bw, const float* f2bb,
    unsigned short* ws)
{
  const int b = blockIdx.x, lane = threadIdx.x;
  if (b < 32) {
    const int cm = b >> 2, n = b & 3;
    const float* W; int ldw, colOff; float sgn = 1.0f;
    switch (cm) {
      case 0:  W = a1win; ldw = 192; colOff = 64;  sgn = -1.0f; break;  // -lp_w2@Wk (rep0)
      case 1:  W = a1win; ldw = 192; colOff = 128; break;               //  lp_w2@Wv
      case 2:  W = f1gw;  ldw = 64;  colOff = 0;   break;
      case 3:  W = f1bw;  ldw = 64;  colOff = 0;   break;
      case 4:  W = a2win; ldw = 192; colOff = 64;  sgn = -1.0f; break;
      case 5:  W = a2win; ldw = 192; colOff = 128; break;
      case 6:  W = f2gw;  ldw = 64;  colOff = 0;   break;
      default: W = f2bw;  ldw = 64;  colOff = 0;   break;
    }
    const int col = colOff + n * 16 + (lane & 15);
    const int kb  = (lane >> 4) * 8;
    short8 r;
    #pragma unroll
    for (int j = 0; j < 8; ++j) {
      const int k = kb + j;                 // 0..31
      float acc = 0.0f;
      for (int m = 0; m < 64; ++m) acc += lpw2[k * 64 + m] * W[(size_t)m * ldw + col];
      r[j] = (short)f2h(sgn * acc);
    }
    *reinterpret_cast<short8*>(ws + (size_t)(WS_COMP + b) * 512 + lane * 8) = r;
  } else {
    const int vb = b - 32;
    const int rep = vb >> 2, which = vb & 3;
    const float* win = rep ? a2win : a1win;
    const float* bin = rep ? a2bin : a1bin;
    const float* W; int ldw, colOff; const float* bias0 = nullptr; float sgn = 1.0f;
    switch (which) {
      case 0:  W = win; ldw = 192; colOff = 64;  sgn = -1.0f; break;        // ckneg
      case 1:  W = win; ldw = 192; colOff = 128; bias0 = bin + 128; break;  // bv'
      case 2:  W = rep ? f2gw : f1gw; ldw = 64; colOff = 0; bias0 = rep ? f2gb : f1gb; break;
      default: W = rep ? f2bw : f1bw; ldw = 64; colOff = 0; bias0 = rep ? f2bb : f1bb; break;
    }
    const int c = lane;
    float acc = 0.0f;
    for (int m = 0; m < 64; ++m) acc += lpb2[m] * W[(size_t)m * ldw + colOff + c];
    acc *= sgn;
    if (bias0) acc += bias0[c];
    float* wsb = reinterpret_cast<float*>(ws + WS_BIAS * 512);
    wsb[rep * 256 + which * 64 + c] = acc;
  }
}

// ============ main kernel helpers ============
// Per-wave LDS: NU sub-tiles of 16 rows x stride 72 fp16 (1152 ushort each).
__device__ __forceinline__ short8 ldA(const unsigned short* Ab, int c) {
  return *reinterpret_cast<const short8*>(Ab + c * 32);
}
__device__ __forceinline__ void stC_pk(unsigned short* Cb, int n, unsigned int p01, unsigned int p23) {
  unsigned short* p = Cb + n * 16;
  p[0]   = (unsigned short)p01;
  p[72]  = (unsigned short)(p01 >> 16);   // ds_write_b16_d16_hi
  p[144] = (unsigned short)p23;
  p[216] = (unsigned short)(p23 >> 16);
}
__device__ __forceinline__ void stC(unsigned short* Cb, int n, f32x4 v) {
  stC_pk(Cb, n, pkrtz(v[0], v[1]), pkrtz(v[2], v[3]));
}
// sum over the 16-lane group, broadcast (DPP row_ror adds — VALU pipe, r10-proven)
__device__ __forceinline__ float rowsum16(float v) {
  float r = v;
  r += __int_as_float(__builtin_amdgcn_update_dpp(
        __float_as_int(r), __float_as_int(r), 0x128, 0xf, 0xf, false)); // row_ror:8
  r += __int_as_float(__builtin_amdgcn_update_dpp(
        __float_as_int(r), __float_as_int(r), 0x124, 0xf, 0xf, false)); // row_ror:4
  r += __int_as_float(__builtin_amdgcn_update_dpp(
        __float_as_int(r), __float_as_int(r), 0x122, 0xf, 0xf, false)); // row_ror:2
  r += __int_as_float(__builtin_amdgcn_update_dpp(
        __float_as_int(r), __float_as_int(r), 0x121, 0xf, 0xf, false)); // row_ror:1
  return r;
}

// ============ main kernel: 4 waves/block, NU x 16 rows/wave ============
// (256,5): r17 runs at 64 VGPR under a 128 cap — headroom unused. 5 blocks/CU
// (cap 102 >= 64-reg footprint, LDS 138KB < 160KB) raises occupancy 40->~50%.
__global__ __launch_bounds__(256, 5) void flow_mfma(
    const float* __restrict__ x, const float* __restrict__ t, const float* __restrict__ y,
    const float* __restrict__ b1b1, const float* __restrict__ b1b2,
    const float* __restrict__ lpb1,
    const float* __restrict__ a1bin, const float* __restrict__ a1bout,
    const float* __restrict__ a2bin, const float* __restrict__ a2bout,
    const float* __restrict__ b2b1, const float* __restrict__ b2b2,
    const float* __restrict__ b3b1, const float* __restrict__ b3b2,
    const float* __restrict__ outb,
    const unsigned short* __restrict__ ws,
    float* __restrict__ out, int Btotal)
{
  __shared__ __align__(16) unsigned short lds[4][NU * 16 * 72];
  const int tid  = threadIdx.x;
  const int lane = tid & 63, wid = tid >> 6;
  const int lrow = lane & 15, grp = lane >> 4;
  const int r0   = (blockIdx.x * 4 + wid) * (NU * 16);
  if (r0 >= Btotal) return;
  unsigned short* T = &lds[wid][0];
  unsigned short* Ab[NU];
  unsigned short* Cb[NU];
  bool act[NU];
  int rbase[NU];   // clamped in-bounds row base per chain (redundant loads when inactive)
  #pragma unroll
  for (int u = 0; u < NU; ++u) {
    Ab[u] = T + u * 1152 + lrow * 72 + grp * 8;   // A-frag read base
    Cb[u] = T + u * 1152 + grp * 288 + lrow;      // C-frag write base
    act[u]   = (r0 + u * 16) < Btotal;
    rbase[u] = act[u] ? (r0 + u * 16) : (Btotal - 16);
  }
  const short8* wsl = reinterpret_cast<const short8*>(ws) + lane;
  const float*  wsb = reinterpret_cast<const float*>(ws + WS_BIAS * 512);

  // ---- h80 A-frags: x (chunks 0,1) + time features (chunk 2, zero-padded 80..95)
  short8 hA0[NU], hA1[NU];
  {
    short8 tF[NU];
    #pragma unroll
    for (int u = 0; u < NU; ++u) {
      const size_t row = (size_t)rbase[u] + lrow;
      const float4* xp = reinterpret_cast<const float4*>(x + row * 64) + grp * 2;
      hA0[u] = pack8(xp[0], xp[1]);
      hA1[u] = pack8(xp[8], xp[9]);
      const float tv = t[row];
      float s = __sinf(3.14159265358979323846f * tv);
      float c = __cosf(3.14159265358979323846f * tv);
      short8 hp;
      #pragma unroll
      for (int j = 0; j < 8; ++j) {
        const float v = (grp == 0) ? s : ((grp == 1) ? c : 0.0f);
        hp[j] = (short)f2h(v);
        const float s2 = 2.0f * s * c;
        const float c2 = 1.0f - 2.0f * s * s;
        s = s2; c = c2;
      }
      tF[u] = hp;
    }
    // block1 w1 (K=80, ReLU)
    #pragma unroll
    for (int n = 0; n < 4; ++n) {
      const short8 B0 = wsl[(WS_B1W1 + n * 3 + 0) * 64];
      const short8 B1 = wsl[(WS_B1W1 + n * 3 + 1) * 64];
      const short8 B2 = wsl[(WS_B1W1 + n * 3 + 2) * 64];
      const float bias = b1b1[n * 16 + lrow];
      #pragma unroll
      for (int u = 0; u < NU; ++u) {
        f32x4 acc = {bias, bias, bias, bias};
        acc = MFMA16(hA0[u], B0, acc);
        acc = MFMA16(hA1[u], B1, acc);
        acc = MFMA16(tF[u],  B2, acc);
        stC(Cb[u], n, relu4(acc));
      }
    }
  }
  #pragma unroll
  for (int u = 0; u < NU; ++u) { hA0[u] = ldA(Ab[u], 0); hA1[u] = ldA(Ab[u], 1); }
  #pragma unroll
  for (int n = 0; n < 4; ++n) {
    const short8 B0 = wsl[(WS_B1W2 + n * 2 + 0) * 64];
    const short8 B1 = wsl[(WS_B1W2 + n * 2 + 1) * 64];
    const float bias = b1b2[n * 16 + lrow];
    #pragma unroll
    for (int u = 0; u < NU; ++u) {
      f32x4 acc = {bias, bias, bias, bias};
      acc = MFMA16(hA0[u], B0, acc);
      acc = MFMA16(hA1[u], B1, acc);
      stC(Cb[u], n, acc);
    }
  }
  #pragma unroll
  for (int u = 0; u < NU; ++u) { hA0[u] = ldA(Ab[u], 0); hA1[u] = ldA(Ab[u], 1); }

  // ---- label projection, stage 1 only: z = relu(y@lp_w1 + lp_b1)  (32-dim)
  short8 zA[NU];
  {
    short8 y0[NU], y1[NU];
    #pragma unroll
    for (int u = 0; u < NU; ++u) {
      const float* yrow = y + ((size_t)rbase[u] + lrow) * 40;
      y0[u] = pack8(*reinterpret_cast<const float4*>(yrow + grp * 8),
                    *reinterpret_cast<const float4*>(yrow + grp * 8 + 4));
      y1[u] = (grp == 0) ? pack8(*reinterpret_cast<const float4*>(yrow + 32),
                                 *reinterpret_cast<const float4*>(yrow + 36))
                         : zero8();
    }
    #pragma unroll
    for (int n = 0; n < 2; ++n) {
      const short8 B0 = wsl[(WS_LPW1 + n * 2 + 0) * 64];
      const short8 B1 = wsl[(WS_LPW1 + n * 2 + 1) * 64];
      const float bias = lpb1[n * 16 + lrow];
      #pragma unroll
      for (int u = 0; u < NU; ++u) {
        f32x4 acc = {bias, bias, bias, bias};
        acc = MFMA16(y0[u], B0, acc);
        acc = MFMA16(y1[u], B1, acc);
        stC(Cb[u], n, relu4(acc));
      }
    }
    #pragma unroll
    for (int u = 0; u < NU; ++u) zA[u] = ldA(Ab[u], 0);
  }

  // ---- two reps of [attention -> FiLM -> residual block]
  // residual carry kept PACKED fp16 (2 uints per (n,u))
  unsigned int hCp01[4][NU], hCp23[4][NU];
  #pragma unroll 1
  for (int rep = 0; rep < 2; ++rep) {
    const int WIN  = rep ? WS_A2WIN  : WS_A1WIN;
    const int WOUT = rep ? WS_A2WOUT : WS_A1WOUT;
    const int CK   = WS_COMP + rep * 16;        // pre-negated lp_w2@Wk
    const int CV   = WS_COMP + rep * 16 + 4;    // lp_w2@Wv
    const int CG   = WS_COMP + rep * 16 + 8;    // lp_w2@gw
    const int CB   = WS_COMP + rep * 16 + 12;   // lp_w2@bw
    const int W1   = rep ? WS_B3W1   : WS_B2W1;
    const int W2   = rep ? WS_B3W2   : WS_B2W2;
    const float* binp  = rep ? a2bin  : a1bin;
    const float* boutp = rep ? a2bout : a1bout;
    const float* w1b   = rep ? b3b1   : b2b1;
    const float* w2b   = rep ? b3b2   : b2b2;
    const float* bcomp = wsb + rep * 256;       // [0:64) ckneg, [64:128) bv', [128:192) g', [192:256) fb'

    // attention per head n — TWO PHASES to cap live frags at 20 (r12-proven)
    #pragma unroll 1
    for (int n = 0; n < 4; ++n) {
      float pr[NU][4];
      {
        const short8 Bq0 = wsl[(WIN + n * 2 + 0) * 64];
        const short8 Bq1 = wsl[(WIN + n * 2 + 1) * 64];
        const short8 Bk0 = wsl[(WIN + (4 + n) * 2 + 0) * 64];
        const short8 Bk1 = wsl[(WIN + (4 + n) * 2 + 1) * 64];
        const short8 BCK = wsl[(CK + n) * 64];
        const float bq = binp[n * 16 + lrow];
        const float ck = bcomp[n * 16 + lrow];
        #pragma unroll
        for (int u = 0; u < NU; ++u) {
          f32x4 q = {bq, bq, bq, bq};
          q = MFMA16(hA0[u], Bq0, q);
          q = MFMA16(hA1[u], Bq1, q);
          f32x4 kd = {ck, ck, ck, ck};
          kd = MFMA16(hA0[u], Bk0, kd);
          kd = MFMA16(hA1[u], Bk1, kd);
          kd = MFMA16(zA[u],  BCK, kd);    // BCK pre-negated
          #pragma unroll
          for (int j = 0; j < 4; ++j) {
            const float d = rowsum16(q[j] * kd[j]);
            pr[u][j] = 1.0f / (1.0f + __expf(-0.25f * d));
          }
        }
      }
      {
        const short8 Bv0 = wsl[(WIN + (8 + n) * 2 + 0) * 64];
        const short8 Bv1 = wsl[(WIN + (8 + n) * 2 + 1) * 64];
        const short8 BCV = wsl[(CV + n) * 64];
        const float bv  = binp[128 + n * 16 + lrow];
        const float bvp = bcomp[64 + n * 16 + lrow];
        #pragma unroll
        for (int u = 0; u < NU; ++u) {
          f32x4 v0 = {bv, bv, bv, bv};
          v0 = MFMA16(hA0[u], Bv0, v0);
          v0 = MFMA16(hA1[u], Bv1, v0);
          f32x4 v1 = {bvp, bvp, bvp, bvp};
          v1 = MFMA16(zA[u], BCV, v1);
          f32x4 ov;
          #pragma unroll
          for (int j = 0; j < 4; ++j) ov[j] = fmaf(pr[u][j], v0[j] - v1[j], v1[j]);
          stC(Cb[u], n, ov);
        }
      }
    }
    #pragma unroll
    for (int u = 0; u < NU; ++u) { hA0[u] = ldA(Ab[u], 0); hA1[u] = ldA(Ab[u], 1); }  // attn out

    // out-proj + FiLM — sequenced frag lifetimes (at -> g -> fb), carry packed fp16
    #pragma unroll
    for (int n = 0; n < 4; ++n) {
      f32x4 at[NU], g[NU];
      {
        const short8 Bo0 = wsl[(WOUT + n * 2 + 0) * 64];
        const short8 Bo1 = wsl[(WOUT + n * 2 + 1) * 64];
        const float bo = boutp[n * 16 + lrow];
        #pragma unroll
        for (int u = 0; u < NU; ++u) {
          at[u] = (f32x4){bo, bo, bo, bo};
          at[u] = MFMA16(hA0[u], Bo0, at[u]);
          at[u] = MFMA16(hA1[u], Bo1, at[u]);
        }
      }
      {
        const short8 BG = wsl[(CG + n) * 64];
        const float gp = bcomp[128 + n * 16 + lrow];
        #pragma unroll
        for (int u = 0; u < NU; ++u) {
          g[u] = (f32x4){gp, gp, gp, gp};
          g[u] = MFMA16(zA[u], BG, g[u]);
        }
      }
      {
        const short8 BB = wsl[(CB + n) * 64];
        const float fbp = bcomp[192 + n * 16 + lrow];
        #pragma unroll
        for (int u = 0; u < NU; ++u) {
          f32x4 fb = {fbp, fbp, fbp, fbp};
          fb = MFMA16(zA[u], BB, fb);
          f32x4 hv;
          #pragma unroll
          for (int j = 0; j < 4; ++j) hv[j] = fmaf(g[u][j], at[u][j], fb[j]);
          const unsigned int p01 = pkrtz(hv[0], hv[1]);
          const unsigned int p23 = pkrtz(hv[2], hv[3]);
          hCp01[n][u] = p01; hCp23[n][u] = p23;
          stC_pk(Cb[u], n, p01, p23);
        }
      }
    }
    #pragma unroll
    for (int u = 0; u < NU; ++u) { hA0[u] = ldA(Ab[u], 0); hA1[u] = ldA(Ab[u], 1); }  // FiLM out

    // residual block: h = h + relu(h@w1+b1) @ w2 + b2
    #pragma unroll
    for (int n = 0; n < 4; ++n) {
      const short8 B0 = wsl[(W1 + n * 2 + 0) * 64];
      const short8 B1 = wsl[(W1 + n * 2 + 1) * 64];
      const float bias = w1b[n * 16 + lrow];
      #pragma unroll
      for (int u = 0; u < NU; ++u) {
        f32x4 acc = {bias, bias, bias, bias};
        acc = MFMA16(hA0[u], B0, acc);
        acc = MFMA16(hA1[u], B1, acc);
        stC(Cb[u], n, relu4(acc));
      }
    }
    #pragma unroll
    for (int u = 0; u < NU; ++u) { hA0[u] = ldA(Ab[u], 0); hA1[u] = ldA(Ab[u], 1); }  // u (hidden)
    #pragma unroll
    for (int n = 0; n < 4; ++n) {
      const short8 B0 = wsl[(W2 + n * 2 + 0) * 64];
      const short8 B1 = wsl[(W2 + n * 2 + 1) * 64];
      const float bias = w2b[n * 16 + lrow];
      #pragma unroll
      for (int u = 0; u < NU; ++u) {
        f32x4 acc = {bias, bias, bias, bias};
        acc = MFMA16(hA0[u], B0, acc);
        acc = MFMA16(hA1[u], B1, acc);
        acc[0] += h_lo(hCp01[n][u]);
        acc[1] += h_hi(hCp01[n][u]);
        acc[2] += h_lo(hCp23[n][u]);
        acc[3] += h_hi(hCp23[n][u]);
        stC(Cb[u], n, acc);
      }
    }
    #pragma unroll
    for (int u = 0; u < NU; ++u) { hA0[u] = ldA(Ab[u], 0); hA1[u] = ldA(Ab[u], 1); }  // next h
  }

  // ---- final projection + store (f32, coalesced 64B per 16-lane group)
  #pragma unroll 1
  for (int n = 0; n < 4; ++n) {
    const short8 B0 = wsl[(WS_OUTW + n * 2 + 0) * 64];
    const short8 B1 = wsl[(WS_OUTW + n * 2 + 1) * 64];
    const float bias = outb[n * 16 + lrow];
    #pragma unroll
    for (int u = 0; u < NU; ++u) {
      f32x4 a = {bias, bias, bias, bias};
      a = MFMA16(hA0[u], B0, a);
      a = MFMA16(hA1[u], B1, a);
      if (act[u]) {
        float* ob = out + ((size_t)rbase[u] + grp * 4) * 64 + n * 16 + lrow;
        #pragma unroll
        for (int j = 0; j < 4; ++j)
          ob[j * 64] = a[j];
      }
    }
  }
}

extern "C" void kernel_launch(void* const* d_in, const int* in_sizes, int n_in,
                              void* d_out, int out_size, void* d_ws, size_t ws_size,
                              hipStream_t stream) {
  (void)n_in; (void)out_size; (void)ws_size;
  const float* p[37];
  for (int i = 0; i < 37; ++i) p[i] = (const float*)d_in[i];
  unsigned short* ws = (unsigned short*)d_ws;

  prep_kernel<<<dim3(164), dim3(64), 0, stream>>>(
      p[23], p[25], p[3], p[5], p[7], p[9], p[15], p[17],
      p[27], p[29], p[11], p[13], p[19], p[21], p[31], p[33], p[35], ws);

  prep2_kernel<<<dim3(40), dim3(64), 0, stream>>>(
      p[5],  p[6],                       // lp_w2, lp_b2
      p[7],  p[8],  p[11], p[12],        // a1_win, a1_bin, a2_win, a2_bin
      p[15], p[16], p[17], p[18],        // f1_gw, f1_gb, f1_bw, f1_bb
      p[19], p[20], p[21], p[22],        // f2_gw, f2_gb, f2_bw, f2_bb
      ws);

  const int B = in_sizes[0] / 64;
  const int rowsPerBlock = 4 * NU * 16;          // 192
  const int grid = (B + rowsPerBlock - 1) / rowsPerBlock;
  flow_mfma<<<dim3(grid), dim3(256), 0, stream>>>(
      p[0], p[1], p[2],
      p[24], p[26],          // b1_b1, b1_b2
      p[4],                  // lp_b1
      p[8],  p[10],          // a1_bin, a1_bout
      p[12], p[14],          // a2_bin, a2_bout
      p[28], p[30],          // b2_b1, b2_b2
      p[32], p[34],          // b3_b1, b3_b2
      p[36],                 // out_b
      ws, (float*)d_out, B);
}

// Round 19
// 185.337 us; speedup vs baseline: 1.5483x; 1.5483x over previous
//
#include <hip/hip_runtime.h>
#include <math.h>

#define NU 3   // independent 16-row chains per wave (48 rows/wave)

typedef __attribute__((ext_vector_type(8))) short   short8;   // 8 fp16 bit-container (4 VGPRs)
typedef __attribute__((ext_vector_type(8))) _Float16 half8;
typedef __attribute__((ext_vector_type(2))) __fp16  fp16x2;   // cvt_pkrtz result type
typedef __attribute__((ext_vector_type(4))) float   f32x4;    // MFMA C/D frag

__device__ __forceinline__ half8 as_h8(short8 s) {
  union { short8 s; half8 h; } u; u.s = s; return u.h;
}
#define MFMA16(a,b,c) __builtin_amdgcn_mfma_f32_16x16x32_f16(as_h8(a), as_h8(b), (c), 0, 0, 0)

// ---- ws layout: frag-blocks of 1024 B (64 lanes x 16 B) ----
#define WS_B1W1   0
#define WS_B1W2   12
#define WS_LPW1   20
#define WS_BIAS   24    // 2 frag blocks reused as f32 bias region (512 floats)
#define WS_A1WIN  28
#define WS_A1WOUT 52
#define WS_B2W1   76
#define WS_B2W2   84
#define WS_A2WIN  92
#define WS_A2WOUT 116
#define WS_B3W1   140
#define WS_B3W2   148
#define WS_OUTW   156
#define WS_COMP   164   // 32 composed frags: per rep r (16): CKneg[4], CV[4], G[4], BF[4]
#define WS_FRAGS  196

// f32 -> fp16 (prep + scalar paths)
__device__ __forceinline__ unsigned short f2h(float f) {
  union { _Float16 h; unsigned short u; } r;
  r.h = (_Float16)f;
  return r.u;
}
// packed f32x2 -> fp16x2 (RTZ), single VALU op
__device__ __forceinline__ unsigned int pkrtz(float lo, float hi) {
  union { fp16x2 h; unsigned int u; } r;
  r.h = __builtin_amdgcn_cvt_pkrtz(lo, hi);
  return r.u;
}
// unpack fp16 halves of a uint -> f32 (v_cvt_f32_f16)
__device__ __forceinline__ float h_lo(unsigned int p) {
  union { unsigned short s; _Float16 h; } c; c.s = (unsigned short)p; return (float)c.h;
}
__device__ __forceinline__ float h_hi(unsigned int p) {
  union { unsigned short s; _Float16 h; } c; c.s = (unsigned short)(p >> 16); return (float)c.h;
}

__device__ __forceinline__ short8 pack8(float4 a, float4 b) {
  union { unsigned int u[4]; short8 s; } r;
  r.u[0] = pkrtz(a.x, a.y);
  r.u[1] = pkrtz(a.z, a.w);
  r.u[2] = pkrtz(b.x, b.y);
  r.u[3] = pkrtz(b.z, b.w);
  return r.s;
}

__device__ __forceinline__ short8 zero8() {
  short8 r;
  #pragma unroll
  for (int j = 0; j < 8; ++j) r[j] = 0;
  return r;
}

__device__ __forceinline__ f32x4 relu4(f32x4 v) {
  f32x4 r;
  #pragma unroll
  for (int j = 0; j < 4; ++j) r[j] = fmaxf(v[j], 0.0f);
  return r;
}

// ============ prep: direct weights f32 -> fp16 B-fragments in d_ws ============
// B-frag layout (16x16x32): lane l holds B[k = (l>>4)*8 + j][col = l&15], j=0..7.
__global__ __launch_bounds__(64) void prep_kernel(
    const float* b1w1, const float* b1w2, const float* lpw1, const float* lpw2,
    const float* a1win, const float* a1wout, const float* f1gw, const float* f1bw,
    const float* b2w1, const float* b2w2, const float* a2win, const float* a2wout,
    const float* f2gw, const float* f2bw, const float* b3w1, const float* b3w2,
    const float* outw, unsigned short* ws)
{
  const float* WS_[17] = {b1w1,b1w2,lpw1,lpw2,a1win,a1wout,f1gw,f1bw,b2w1,b2w2,
                          a2win,a2wout,f2gw,f2bw,b3w1,b3w2,outw};
  const int KA[17] = {80,64,40,32,64,64,64,64,64,64,64,64,64,64,64,64,64};
  const int NA[17] = {64,64,32,64,192,64,64,64,64,64,192,64,64,64,64,64,64};
  const int FO[17] = {0,12,20,24,28,52,60,68,76,84,92,116,124,132,140,148,156};

  const int b = blockIdx.x;
  int m = 0;
  #pragma unroll
  for (int i = 1; i < 17; ++i) if (b >= FO[i]) m = i;
  const int f  = b - FO[m];
  const int K  = KA[m], N = NA[m];
  const int kc = (K + 31) >> 5;
  const int n  = f / kc, c = f % kc;

  const int lane = threadIdx.x;
  const int col  = n * 16 + (lane & 15);
  const int kb   = c * 32 + ((lane >> 4) * 8);
  const float* W = WS_[m];

  short8 r;
  #pragma unroll
  for (int j = 0; j < 8; ++j) {
    const int k = kb + j;
    const float v = (k < K) ? W[(size_t)k * N + col] : 0.0f;
    r[j] = (short)f2h(v);
  }
  *reinterpret_cast<short8*>(ws + (size_t)b * 512 + lane * 8) = r;
}

// ============ prep2: composed ye-path matrices and biases ============
// ye = z@lp_w2 + lp_b2  =>  ye@W = z@(lp_w2@W) + (lp_b2@W).
__global__ __launch_bounds__(64) void prep2_kernel(
    const float* lpw2, const float* lpb2,
    const float* a1win, const float* a1bin, const float* a2win, const float* a2bin,
    const float* f1gw, const float* f1gb, const float* f1bw, const float* f1bb,
    const float* f2gw, const float* f2gb, const float* f2bw, const float* f2bb,
    unsigned short* ws)
{
  const int b = blockIdx.x, lane = threadIdx.x;
  if (b < 32) {
    const int cm = b >> 2, n = b & 3;
    const float* W; int ldw, colOff; float sgn = 1.0f;
    switch (cm) {
      case 0:  W = a1win; ldw = 192; colOff = 64;  sgn = -1.0f; break;  // -lp_w2@Wk (rep0)
      case 1:  W = a1win; ldw = 192; colOff = 128; break;               //  lp_w2@Wv
      case 2:  W = f1gw;  ldw = 64;  colOff = 0;   break;
      case 3:  W = f1bw;  ldw = 64;  colOff = 0;   break;
      case 4:  W = a2win; ldw = 192; colOff = 64;  sgn = -1.0f; break;
      case 5:  W = a2win; ldw = 192; colOff = 128; break;
      case 6:  W = f2gw;  ldw = 64;  colOff = 0;   break;
      default: W = f2bw;  ldw = 64;  colOff = 0;   break;
    }
    const int col = colOff + n * 16 + (lane & 15);
    const int kb  = (lane >> 4) * 8;
    short8 r;
    #pragma unroll
    for (int j = 0; j < 8; ++j) {
      const int k = kb + j;                 // 0..31
      float acc = 0.0f;
      for (int m = 0; m < 64; ++m) acc += lpw2[k * 64 + m] * W[(size_t)m * ldw + col];
      r[j] = (short)f2h(sgn * acc);
    }
    *reinterpret_cast<short8*>(ws + (size_t)(WS_COMP + b) * 512 + lane * 8) = r;
  } else {
    const int vb = b - 32;
    const int rep = vb >> 2, which = vb & 3;
    const float* win = rep ? a2win : a1win;
    const float* bin = rep ? a2bin : a1bin;
    const float* W; int ldw, colOff; const float* bias0 = nullptr; float sgn = 1.0f;
    switch (which) {
      case 0:  W = win; ldw = 192; colOff = 64;  sgn = -1.0f; break;        // ckneg
      case 1:  W = win; ldw = 192; colOff = 128; bias0 = bin + 128; break;  // bv'
      case 2:  W = rep ? f2gw : f1gw; ldw = 64; colOff = 0; bias0 = rep ? f2gb : f1gb; break;
      default: W = rep ? f2bw : f1bw; ldw = 64; colOff = 0; bias0 = rep ? f2bb : f1bb; break;
    }
    const int c = lane;
    float acc = 0.0f;
    for (int m = 0; m < 64; ++m) acc += lpb2[m] * W[(size_t)m * ldw + colOff + c];
    acc *= sgn;
    if (bias0) acc += bias0[c];
    float* wsb = reinterpret_cast<float*>(ws + WS_BIAS * 512);
    wsb[rep * 256 + which * 64 + c] = acc;
  }
}

// ============ main kernel helpers ============
// Per-wave LDS: NU sub-tiles of 16 rows x stride 72 fp16 (1152 ushort each).
__device__ __forceinline__ short8 ldA(const unsigned short* Ab, int c) {
  return *reinterpret_cast<const short8*>(Ab + c * 32);
}
__device__ __forceinline__ void stC_pk(unsigned short* Cb, int n, unsigned int p01, unsigned int p23) {
  unsigned short* p = Cb + n * 16;
  p[0]   = (unsigned short)p01;
  p[72]  = (unsigned short)(p01 >> 16);   // ds_write_b16_d16_hi
  p[144] = (unsigned short)p23;
  p[216] = (unsigned short)(p23 >> 16);
}
__device__ __forceinline__ void stC(unsigned short* Cb, int n, f32x4 v) {
  stC_pk(Cb, n, pkrtz(v[0], v[1]), pkrtz(v[2], v[3]));
}
// sum over the 16-lane group, broadcast (DPP row_ror adds — VALU pipe, r10-proven)
__device__ __forceinline__ float rowsum16(float v) {
  float r = v;
  r += __int_as_float(__builtin_amdgcn_update_dpp(
        __float_as_int(r), __float_as_int(r), 0x128, 0xf, 0xf, false)); // row_ror:8
  r += __int_as_float(__builtin_amdgcn_update_dpp(
        __float_as_int(r), __float_as_int(r), 0x124, 0xf, 0xf, false)); // row_ror:4
  r += __int_as_float(__builtin_amdgcn_update_dpp(
        __float_as_int(r), __float_as_int(r), 0x122, 0xf, 0xf, false)); // row_ror:2
  r += __int_as_float(__builtin_amdgcn_update_dpp(
        __float_as_int(r), __float_as_int(r), 0x121, 0xf, 0xf, false)); // row_ror:1
  return r;
}

// ============ main kernel: 4 waves/block, NU x 16 rows/wave ============
// (256,4) = verified best (r17: 185.7us, VGPR 64, zero spill, 40% occ).
// (256,5)/(256,8) both squeeze the allocator below the working set -> spills.
__global__ __launch_bounds__(256, 4) void flow_mfma(
    const float* __restrict__ x, const float* __restrict__ t, const float* __restrict__ y,
    const float* __restrict__ b1b1, const float* __restrict__ b1b2,
    const float* __restrict__ lpb1,
    const float* __restrict__ a1bin, const float* __restrict__ a1bout,
    const float* __restrict__ a2bin, const float* __restrict__ a2bout,
    const float* __restrict__ b2b1, const float* __restrict__ b2b2,
    const float* __restrict__ b3b1, const float* __restrict__ b3b2,
    const float* __restrict__ outb,
    const unsigned short* __restrict__ ws,
    float* __restrict__ out, int Btotal)
{
  __shared__ __align__(16) unsigned short lds[4][NU * 16 * 72];
  const int tid  = threadIdx.x;
  const int lane = tid & 63, wid = tid >> 6;
  const int lrow = lane & 15, grp = lane >> 4;
  const int r0   = (blockIdx.x * 4 + wid) * (NU * 16);
  if (r0 >= Btotal) return;
  unsigned short* T = &lds[wid][0];
  unsigned short* Ab[NU];
  unsigned short* Cb[NU];
  bool act[NU];
  int rbase[NU];   // clamped in-bounds row base per chain (redundant loads when inactive)
  #pragma unroll
  for (int u = 0; u < NU; ++u) {
    Ab[u] = T + u * 1152 + lrow * 72 + grp * 8;   // A-frag read base
    Cb[u] = T + u * 1152 + grp * 288 + lrow;      // C-frag write base
    act[u]   = (r0 + u * 16) < Btotal;
    rbase[u] = act[u] ? (r0 + u * 16) : (Btotal - 16);
  }
  const short8* wsl = reinterpret_cast<const short8*>(ws) + lane;
  const float*  wsb = reinterpret_cast<const float*>(ws + WS_BIAS * 512);

  // ---- h80 A-frags: x (chunks 0,1) + time features (chunk 2, zero-padded 80..95)
  short8 hA0[NU], hA1[NU];
  {
    short8 tF[NU];
    #pragma unroll
    for (int u = 0; u < NU; ++u) {
      const size_t row = (size_t)rbase[u] + lrow;
      const float4* xp = reinterpret_cast<const float4*>(x + row * 64) + grp * 2;
      hA0[u] = pack8(xp[0], xp[1]);
      hA1[u] = pack8(xp[8], xp[9]);
      const float tv = t[row];
      float s = __sinf(3.14159265358979323846f * tv);
      float c = __cosf(3.14159265358979323846f * tv);
      short8 hp;
      #pragma unroll
      for (int j = 0; j < 8; ++j) {
        const float v = (grp == 0) ? s : ((grp == 1) ? c : 0.0f);
        hp[j] = (short)f2h(v);
        const float s2 = 2.0f * s * c;
        const float c2 = 1.0f - 2.0f * s * s;
        s = s2; c = c2;
      }
      tF[u] = hp;
    }
    // block1 w1 (K=80, ReLU)
    #pragma unroll
    for (int n = 0; n < 4; ++n) {
      const short8 B0 = wsl[(WS_B1W1 + n * 3 + 0) * 64];
      const short8 B1 = wsl[(WS_B1W1 + n * 3 + 1) * 64];
      const short8 B2 = wsl[(WS_B1W1 + n * 3 + 2) * 64];
      const float bias = b1b1[n * 16 + lrow];
      #pragma unroll
      for (int u = 0; u < NU; ++u) {
        f32x4 acc = {bias, bias, bias, bias};
        acc = MFMA16(hA0[u], B0, acc);
        acc = MFMA16(hA1[u], B1, acc);
        acc = MFMA16(tF[u],  B2, acc);
        stC(Cb[u], n, relu4(acc));
      }
    }
  }
  #pragma unroll
  for (int u = 0; u < NU; ++u) { hA0[u] = ldA(Ab[u], 0); hA1[u] = ldA(Ab[u], 1); }
  #pragma unroll
  for (int n = 0; n < 4; ++n) {
    const short8 B0 = wsl[(WS_B1W2 + n * 2 + 0) * 64];
    const short8 B1 = wsl[(WS_B1W2 + n * 2 + 1) * 64];
    const float bias = b1b2[n * 16 + lrow];
    #pragma unroll
    for (int u = 0; u < NU; ++u) {
      f32x4 acc = {bias, bias, bias, bias};
      acc = MFMA16(hA0[u], B0, acc);
      acc = MFMA16(hA1[u], B1, acc);
      stC(Cb[u], n, acc);
    }
  }
  #pragma unroll
  for (int u = 0; u < NU; ++u) { hA0[u] = ldA(Ab[u], 0); hA1[u] = ldA(Ab[u], 1); }

  // ---- label projection, stage 1 only: z = relu(y@lp_w1 + lp_b1)  (32-dim)
  short8 zA[NU];
  {
    short8 y0[NU], y1[NU];
    #pragma unroll
    for (int u = 0; u < NU; ++u) {
      const float* yrow = y + ((size_t)rbase[u] + lrow) * 40;
      y0[u] = pack8(*reinterpret_cast<const float4*>(yrow + grp * 8),
                    *reinterpret_cast<const float4*>(yrow + grp * 8 + 4));
      y1[u] = (grp == 0) ? pack8(*reinterpret_cast<const float4*>(yrow + 32),
                                 *reinterpret_cast<const float4*>(yrow + 36))
                         : zero8();
    }
    #pragma unroll
    for (int n = 0; n < 2; ++n) {
      const short8 B0 = wsl[(WS_LPW1 + n * 2 + 0) * 64];
      const short8 B1 = wsl[(WS_LPW1 + n * 2 + 1) * 64];
      const float bias = lpb1[n * 16 + lrow];
      #pragma unroll
      for (int u = 0; u < NU; ++u) {
        f32x4 acc = {bias, bias, bias, bias};
        acc = MFMA16(y0[u], B0, acc);
        acc = MFMA16(y1[u], B1, acc);
        stC(Cb[u], n, relu4(acc));
      }
    }
    #pragma unroll
    for (int u = 0; u < NU; ++u) zA[u] = ldA(Ab[u], 0);
  }

  // ---- two reps of [attention -> FiLM -> residual block]
  // residual carry kept PACKED fp16 (2 uints per (n,u))
  unsigned int hCp01[4][NU], hCp23[4][NU];
  #pragma unroll 1
  for (int rep = 0; rep < 2; ++rep) {
    const int WIN  = rep ? WS_A2WIN  : WS_A1WIN;
    const int WOUT = rep ? WS_A2WOUT : WS_A1WOUT;
    const int CK   = WS_COMP + rep * 16;        // pre-negated lp_w2@Wk
    const int CV   = WS_COMP + rep * 16 + 4;    // lp_w2@Wv
    const int CG   = WS_COMP + rep * 16 + 8;    // lp_w2@gw
    const int CB   = WS_COMP + rep * 16 + 12;   // lp_w2@bw
    const int W1   = rep ? WS_B3W1   : WS_B2W1;
    const int W2   = rep ? WS_B3W2   : WS_B2W2;
    const float* binp  = rep ? a2bin  : a1bin;
    const float* boutp = rep ? a2bout : a1bout;
    const float* w1b   = rep ? b3b1   : b2b1;
    const float* w2b   = rep ? b3b2   : b2b2;
    const float* bcomp = wsb + rep * 256;       // [0:64) ckneg, [64:128) bv', [128:192) g', [192:256) fb'

    // attention per head n — TWO PHASES to cap live frags at 20 (r12-proven)
    #pragma unroll 1
    for (int n = 0; n < 4; ++n) {
      float pr[NU][4];
      {
        const short8 Bq0 = wsl[(WIN + n * 2 + 0) * 64];
        const short8 Bq1 = wsl[(WIN + n * 2 + 1) * 64];
        const short8 Bk0 = wsl[(WIN + (4 + n) * 2 + 0) * 64];
        const short8 Bk1 = wsl[(WIN + (4 + n) * 2 + 1) * 64];
        const short8 BCK = wsl[(CK + n) * 64];
        const float bq = binp[n * 16 + lrow];
        const float ck = bcomp[n * 16 + lrow];
        #pragma unroll
        for (int u = 0; u < NU; ++u) {
          f32x4 q = {bq, bq, bq, bq};
          q = MFMA16(hA0[u], Bq0, q);
          q = MFMA16(hA1[u], Bq1, q);
          f32x4 kd = {ck, ck, ck, ck};
          kd = MFMA16(hA0[u], Bk0, kd);
          kd = MFMA16(hA1[u], Bk1, kd);
          kd = MFMA16(zA[u],  BCK, kd);    // BCK pre-negated
          #pragma unroll
          for (int j = 0; j < 4; ++j) {
            const float d = rowsum16(q[j] * kd[j]);
            pr[u][j] = 1.0f / (1.0f + __expf(-0.25f * d));
          }
        }
      }
      {
        const short8 Bv0 = wsl[(WIN + (8 + n) * 2 + 0) * 64];
        const short8 Bv1 = wsl[(WIN + (8 + n) * 2 + 1) * 64];
        const short8 BCV = wsl[(CV + n) * 64];
        const float bv  = binp[128 + n * 16 + lrow];
        const float bvp = bcomp[64 + n * 16 + lrow];
        #pragma unroll
        for (int u = 0; u < NU; ++u) {
          f32x4 v0 = {bv, bv, bv, bv};
          v0 = MFMA16(hA0[u], Bv0, v0);
          v0 = MFMA16(hA1[u], Bv1, v0);
          f32x4 v1 = {bvp, bvp, bvp, bvp};
          v1 = MFMA16(zA[u], BCV, v1);
          f32x4 ov;
          #pragma unroll
          for (int j = 0; j < 4; ++j) ov[j] = fmaf(pr[u][j], v0[j] - v1[j], v1[j]);
          stC(Cb[u], n, ov);
        }
      }
    }
    #pragma unroll
    for (int u = 0; u < NU; ++u) { hA0[u] = ldA(Ab[u], 0); hA1[u] = ldA(Ab[u], 1); }  // attn out

    // out-proj + FiLM — sequenced frag lifetimes (at -> g -> fb), carry packed fp16
    #pragma unroll
    for (int n = 0; n < 4; ++n) {
      f32x4 at[NU], g[NU];
      {
        const short8 Bo0 = wsl[(WOUT + n * 2 + 0) * 64];
        const short8 Bo1 = wsl[(WOUT + n * 2 + 1) * 64];
        const float bo = boutp[n * 16 + lrow];
        #pragma unroll
        for (int u = 0; u < NU; ++u) {
          at[u] = (f32x4){bo, bo, bo, bo};
          at[u] = MFMA16(hA0[u], Bo0, at[u]);
          at[u] = MFMA16(hA1[u], Bo1, at[u]);
        }
      }
      {
        const short8 BG = wsl[(CG + n) * 64];
        const float gp = bcomp[128 + n * 16 + lrow];
        #pragma unroll
        for (int u = 0; u < NU; ++u) {
          g[u] = (f32x4){gp, gp, gp, gp};
          g[u] = MFMA16(zA[u], BG, g[u]);
        }
      }
      {
        const short8 BB = wsl[(CB + n) * 64];
        const float fbp = bcomp[192 + n * 16 + lrow];
        #pragma unroll
        for (int u = 0; u < NU; ++u) {
          f32x4 fb = {fbp, fbp, fbp, fbp};
          fb = MFMA16(zA[u], BB, fb);
          f32x4 hv;
          #pragma unroll
          for (int j = 0; j < 4; ++j) hv[j] = fmaf(g[u][j], at[u][j], fb[j]);
          const unsigned int p01 = pkrtz(hv[0], hv[1]);
          const unsigned int p23 = pkrtz(hv[2], hv[3]);
          hCp01[n][u] = p01; hCp23[n][u] = p23;
          stC_pk(Cb[u], n, p01, p23);
        }
      }
    }
    #pragma unroll
    for (int u = 0; u < NU; ++u) { hA0[u] = ldA(Ab[u], 0); hA1[u] = ldA(Ab[u], 1); }  // FiLM out

    // residual block: h = h + relu(h@w1+b1) @ w2 + b2
    #pragma unroll
    for (int n = 0; n < 4; ++n) {
      const short8 B0 = wsl[(W1 + n * 2 + 0) * 64];
      const short8 B1 = wsl[(W1 + n * 2 + 1) * 64];
      const float bias = w1b[n * 16 + lrow];
      #pragma unroll
      for (int u = 0; u < NU; ++u) {
        f32x4 acc = {bias, bias, bias, bias};
        acc = MFMA16(hA0[u], B0, acc);
        acc = MFMA16(hA1[u], B1, acc);
        stC(Cb[u], n, relu4(acc));
      }
    }
    #pragma unroll
    for (int u = 0; u < NU; ++u) { hA0[u] = ldA(Ab[u], 0); hA1[u] = ldA(Ab[u], 1); }  // u (hidden)
    #pragma unroll
    for (int n = 0; n < 4; ++n) {
      const short8 B0 = wsl[(W2 + n * 2 + 0) * 64];
      const short8 B1 = wsl[(W2 + n * 2 + 1) * 64];
      const float bias = w2b[n * 16 + lrow];
      #pragma unroll
      for (int u = 0; u < NU; ++u) {
        f32x4 acc = {bias, bias, bias, bias};
        acc = MFMA16(hA0[u], B0, acc);
        acc = MFMA16(hA1[u], B1, acc);
        acc[0] += h_lo(hCp01[n][u]);
        acc[1] += h_hi(hCp01[n][u]);
        acc[2] += h_lo(hCp23[n][u]);
        acc[3] += h_hi(hCp23[n][u]);
        stC(Cb[u], n, acc);
      }
    }
    #pragma unroll
    for (int u = 0; u < NU; ++u) { hA0[u] = ldA(Ab[u], 0); hA1[u] = ldA(Ab[u], 1); }  // next h
  }

  // ---- final projection + store (f32, coalesced 64B per 16-lane group)
  #pragma unroll 1
  for (int n = 0; n < 4; ++n) {
    const short8 B0 = wsl[(WS_OUTW + n * 2 + 0) * 64];
    const short8 B1 = wsl[(WS_OUTW + n * 2 + 1) * 64];
    const float bias = outb[n * 16 + lrow];
    #pragma unroll
    for (int u = 0; u < NU; ++u) {
      f32x4 a = {bias, bias, bias, bias};
      a = MFMA16(hA0[u], B0, a);
      a = MFMA16(hA1[u], B1, a);
      if (act[u]) {
        float* ob = out + ((size_t)rbase[u] + grp * 4) * 64 + n * 16 + lrow;
        #pragma unroll
        for (int j = 0; j < 4; ++j)
          ob[j * 64] = a[j];
      }
    }
  }
}

extern "C" void kernel_launch(void* const* d_in, const int* in_sizes, int n_in,
                              void* d_out, int out_size, void* d_ws, size_t ws_size,
                              hipStream_t stream) {
  (void)n_in; (void)out_size; (void)ws_size;
  const float* p[37];
  for (int i = 0; i < 37; ++i) p[i] = (const float*)d_in[i];
  unsigned short* ws = (unsigned short*)d_ws;

  prep_kernel<<<dim3(164), dim3(64), 0, stream>>>(
      p[23], p[25], p[3], p[5], p[7], p[9], p[15], p[17],
      p[27], p[29], p[11], p[13], p[19], p[21], p[31], p[33], p[35], ws);

  prep2_kernel<<<dim3(40), dim3(64), 0, stream>>>(
      p[5],  p[6],                       // lp_w2, lp_b2
      p[7],  p[8],  p[11], p[12],        // a1_win, a1_bin, a2_win, a2_bin
      p[15], p[16], p[17], p[18],        // f1_gw, f1_gb, f1_bw, f1_bb
      p[19], p[20], p[21], p[22],        // f2_gw, f2_gb, f2_bw, f2_bb
      ws);

  const int B = in_sizes[0] / 64;
  const int rowsPerBlock = 4 * NU * 16;          // 192
  const int grid = (B + rowsPerBlock - 1) / rowsPerBlock;
  flow_mfma<<<dim3(grid), dim3(256), 0, stream>>>(
      p[0], p[1], p[2],
      p[24], p[26],          // b1_b1, b1_b2
      p[4],                  // lp_b1
      p[8],  p[10],          // a1_bin, a1_bout
      p[12], p[14],          // a2_bin, a2_bout
      p[28], p[30],          // b2_b1, b2_b2
      p[32], p[34],          // b3_b1, b3_b2
      p[36],                 // out_b
      ws, (float*)d_out, B);
}